// Round 8
// baseline (414.571 us; speedup 1.0000x reference)
//
#include <hip/hip_runtime.h>

// AttentionHead: B=16384, W=10, D=1024, K=V=64
// out[b,i,:] = softmax_j( min(k_i . q_j, tri) ) @ v    (scores row = key index)
//
// GEMM front-end: 6-term split-bf16 MFMA (x,w in 3 bf16 pieces; products
// hh,hm,mh,hl,mm,lh) -> fp32-grade projections. f64 attention epilogue
// (round-5/7 proven math). FLOAT32 output.
//
// Round-8 scheduling: double-buffered A staging, ONE barrier per chunk,
// next-chunk x loads issued before the MFMA phase (T14 issue-early /
// write-late) so HBM latency hides under MFMA + W L2 loads.

#define D 1024
#define BM 80            // 8 batches of 10 rows per block
#define KCHUNKS 16       // 1024 / 64
#define ASTR 72          // staged row stride in shorts (64 data + 8 pad)
#define ABUF 34560       // bytes per staging buffer set (3 pieces x 80 x 72 x 2B)
#define APIECE 11520     // bytes per piece [80][ASTR]
#define KSTR 197         // kqv row stride in floats (odd -> fewer bank conflicts)

typedef __attribute__((ext_vector_type(8))) short bf16x8;
typedef __attribute__((ext_vector_type(4))) float f32x4;
typedef __attribute__((ext_vector_type(4))) unsigned short u16x4;

static __device__ __forceinline__ unsigned short f2bf_rtne(float f) {
    unsigned int u = __builtin_bit_cast(unsigned int, f);
    u += 0x7fffu + ((u >> 16) & 1u);
    return (unsigned short)(u >> 16);
}
static __device__ __forceinline__ float bf2f(unsigned short h) {
    unsigned int u = ((unsigned int)h) << 16;
    return __builtin_bit_cast(float, u);
}

// --- kernel0: split wk|wq|wv into transposed bf16 3-piece Wt[n][k]
__global__ __launch_bounds__(256) void prep_w(const float* __restrict__ wk,
                                              const float* __restrict__ wq,
                                              const float* __restrict__ wv,
                                              unsigned short* __restrict__ wth,
                                              unsigned short* __restrict__ wtm,
                                              unsigned short* __restrict__ wtl) {
    int idx = blockIdx.x * 256 + threadIdx.x;   // idx = n*1024 + kk, n in [0,192)
    int n  = idx >> 10;
    int kk = idx & 1023;
    const float* src = (n < 64) ? wk : (n < 128) ? wq : wv;
    float w = src[kk * 64 + (n & 63)];
    unsigned short h = f2bf_rtne(w);
    float r1 = w - bf2f(h);                     // exact
    unsigned short m = f2bf_rtne(r1);
    float r2 = r1 - bf2f(m);                    // exact
    wth[idx] = h;
    wtm[idx] = m;
    wtl[idx] = f2bf_rtne(r2);
}

// --- kernel1: fused 6-term projection GEMM + f64 attention
__global__ __launch_bounds__(256, 2) void fused_attn(
        const float* __restrict__ x,
        const unsigned short* __restrict__ wth,
        const unsigned short* __restrict__ wtm,
        const unsigned short* __restrict__ wtl,
        float* __restrict__ out) {

    __shared__ char smem[69120];                 // 2 x ABUF staging (union w/ kqv)
    float*  kqv = (float*)smem;                  // epilogue: [80][KSTR] = 63040 B
    double* scd = (double*)(smem + 63040);       // 4 waves x 110 f64 = 3520 B

    const int tid  = threadIdx.x;
    const int wave = tid >> 6;
    const int lane = tid & 63;
    const int m0   = blockIdx.x * BM;
    const int nbase = wave * 48;          // 3 n-tiles of 16 per wave (192 total)
    const int arow  = lane & 15;
    const int apart = lane >> 4;          // 0..3

    // ---------- layout probe: discover acc (lane,reg) -> (row, col) ----------
    unsigned short* AhS0 = (unsigned short*)smem;
    for (int i = tid; i < 80 * ASTR; i += 256) AhS0[i] = 0;
    __syncthreads();
    if (tid < 80) AhS0[tid * ASTR] = f2bf_rtne((float)(tid + 1));  // A[m][0]=m+1
    __syncthreads();
    bf16x8 aprobe = *reinterpret_cast<const bf16x8*>((char*)AhS0 + arow * (ASTR * 2) + apart * 16);
    bf16x8 bone = {}, aone = {}, bcol = {};
    if (apart == 0) {
        bone[0] = (short)0x3F80;                              // B[0][n] = 1
        aone[0] = (short)0x3F80;                              // A[m][0] = 1
        bcol[0] = (short)f2bf_rtne((float)(arow + 1));        // B[0][n] = n+1
    }
    f32x4 z = {0.f, 0.f, 0.f, 0.f};
    f32x4 d1 = __builtin_amdgcn_mfma_f32_16x16x32_bf16(aprobe, bone, z, 0, 0, 0); // row+1
    f32x4 d2 = __builtin_amdgcn_mfma_f32_16x16x32_bf16(aone,  bcol, z, 0, 0, 0);  // col+1
    int R[4], Cc[4];
    #pragma unroll
    for (int r = 0; r < 4; ++r) {
        R[r]  = (int)(d1[r] + 0.5f) - 1;
        Cc[r] = (int)(d2[r] + 0.5f) - 1;
    }
    __syncthreads();

    // per-thread staging coords (p = tid + it*256 -> row, col)
    int srow[5], scol[5];
    #pragma unroll
    for (int it = 0; it < 5; ++it) {
        int p = tid + it * 256;
        srow[it] = p >> 4;
        scol[it] = (p & 15) << 2;
    }

    // ---------- GEMM: kqv[80][192] = x @ [wk|wq|wv], 6-term split ----------
    f32x4 acc[5][3] = {};                 // 5 m-tiles x 3 n-tiles

    // prologue: stage chunk 0 into buf 0
    {
        float4 xv[5];
        #pragma unroll
        for (int it = 0; it < 5; ++it)
            xv[it] = *reinterpret_cast<const float4*>(
                x + (size_t)(m0 + srow[it]) * D + scol[it]);
        char* base = smem;
        #pragma unroll
        for (int it = 0; it < 5; ++it) {
            u16x4 hh, mm, ll;
            #pragma unroll
            for (int e = 0; e < 4; ++e) {
                float xe = (e == 0) ? xv[it].x : (e == 1) ? xv[it].y : (e == 2) ? xv[it].z : xv[it].w;
                unsigned short h = (unsigned short)(__builtin_bit_cast(unsigned int, xe) >> 16);
                float r1 = xe - bf2f(h);
                unsigned short mq = (unsigned short)(__builtin_bit_cast(unsigned int, r1) >> 16);
                float r2 = r1 - bf2f(mq);
                hh[e] = h; mm[e] = mq;
                ll[e] = (unsigned short)(__builtin_bit_cast(unsigned int, r2) >> 16);
            }
            int ro = srow[it] * ASTR + scol[it];
            *reinterpret_cast<u16x4*>((unsigned short*)(base)            + ro) = hh;
            *reinterpret_cast<u16x4*>((unsigned short*)(base + APIECE)   + ro) = mm;
            *reinterpret_cast<u16x4*>((unsigned short*)(base + 2*APIECE) + ro) = ll;
        }
    }
    __syncthreads();

    for (int t = 0; t < KCHUNKS; ++t) {
        const int cur = t & 1;
        char* curb = smem + (cur ? ABUF : 0);
        char* nxtb = smem + (cur ? 0 : ABUF);

        // issue next chunk's x loads EARLY (latency hides under MFMA phase)
        float4 xv[5];
        if (t < KCHUNKS - 1) {
            #pragma unroll
            for (int it = 0; it < 5; ++it)
                xv[it] = *reinterpret_cast<const float4*>(
                    x + (size_t)(m0 + srow[it]) * D + (t + 1) * 64 + scol[it]);
        }

        // MFMA phase on current buffer
        #pragma unroll
        for (int ks = 0; ks < 2; ++ks) {
            bf16x8 wfh[3], wfm[3], wfl[3];
            #pragma unroll
            for (int nt = 0; nt < 3; ++nt) {
                int n = nbase + nt * 16 + arow;
                size_t off = (size_t)n * D + t * 64 + ks * 32 + apart * 8;
                wfh[nt] = *reinterpret_cast<const bf16x8*>(wth + off);
                wfm[nt] = *reinterpret_cast<const bf16x8*>(wtm + off);
                wfl[nt] = *reinterpret_cast<const bf16x8*>(wtl + off);
            }
            #pragma unroll
            for (int mt = 0; mt < 5; ++mt) {
                int ab = (mt * 16 + arow) * (ASTR * 2) + (ks * 4 + apart) * 16;
                bf16x8 ah = *reinterpret_cast<const bf16x8*>(curb + ab);
                bf16x8 am = *reinterpret_cast<const bf16x8*>(curb + APIECE + ab);
                bf16x8 al = *reinterpret_cast<const bf16x8*>(curb + 2*APIECE + ab);
                #pragma unroll
                for (int nt = 0; nt < 3; ++nt) {
                    acc[mt][nt] = __builtin_amdgcn_mfma_f32_16x16x32_bf16(ah, wfh[nt], acc[mt][nt], 0, 0, 0);
                    acc[mt][nt] = __builtin_amdgcn_mfma_f32_16x16x32_bf16(ah, wfm[nt], acc[mt][nt], 0, 0, 0);
                    acc[mt][nt] = __builtin_amdgcn_mfma_f32_16x16x32_bf16(am, wfh[nt], acc[mt][nt], 0, 0, 0);
                    acc[mt][nt] = __builtin_amdgcn_mfma_f32_16x16x32_bf16(ah, wfl[nt], acc[mt][nt], 0, 0, 0);
                    acc[mt][nt] = __builtin_amdgcn_mfma_f32_16x16x32_bf16(am, wfm[nt], acc[mt][nt], 0, 0, 0);
                    acc[mt][nt] = __builtin_amdgcn_mfma_f32_16x16x32_bf16(al, wfh[nt], acc[mt][nt], 0, 0, 0);
                }
            }
        }

        // convert + write next chunk into the OTHER buffer (write-late)
        if (t < KCHUNKS - 1) {
            #pragma unroll
            for (int it = 0; it < 5; ++it) {
                u16x4 hh, mm, ll;
                #pragma unroll
                for (int e = 0; e < 4; ++e) {
                    float xe = (e == 0) ? xv[it].x : (e == 1) ? xv[it].y : (e == 2) ? xv[it].z : xv[it].w;
                    unsigned short h = (unsigned short)(__builtin_bit_cast(unsigned int, xe) >> 16);
                    float r1 = xe - bf2f(h);
                    unsigned short mq = (unsigned short)(__builtin_bit_cast(unsigned int, r1) >> 16);
                    float r2 = r1 - bf2f(mq);
                    hh[e] = h; mm[e] = mq;
                    ll[e] = (unsigned short)(__builtin_bit_cast(unsigned int, r2) >> 16);
                }
                int ro = srow[it] * ASTR + scol[it];
                *reinterpret_cast<u16x4*>((unsigned short*)(nxtb)            + ro) = hh;
                *reinterpret_cast<u16x4*>((unsigned short*)(nxtb + APIECE)   + ro) = mm;
                *reinterpret_cast<u16x4*>((unsigned short*)(nxtb + 2*APIECE) + ro) = ll;
            }
        }
        __syncthreads();   // one barrier per chunk: next buf ready, cur buf free
    }

    // ---------- epilogue: dump all 80 rows, then f64 attention ----------
    #pragma unroll
    for (int mt = 0; mt < 5; ++mt) {
        #pragma unroll
        for (int r = 0; r < 4; ++r) {
            int row = mt * 16 + R[r];
            #pragma unroll
            for (int nt = 0; nt < 3; ++nt)
                kqv[row * KSTR + nbase + nt * 16 + Cc[r]] = acc[mt][nt][r];
        }
    }
    __syncthreads();

    double* sc = scd + wave * 110;
    for (int bb = 0; bb < 2; ++bb) {
        const int bloc = wave * 2 + bb;       // 0..7 within block
        const int r0   = bloc * 10;
        // scores: s[i][j] = k_i . q_j (f64), masked
        #pragma unroll
        for (int it = 0; it < 2; ++it) {
            int p = it * 64 + lane;
            if (p < 100) {
                int i = p / 10;
                int j = p - i * 10;
                double s = 0.0;
                #pragma unroll 8
                for (int c = 0; c < 64; ++c)
                    s += (double)kqv[(r0 + i) * KSTR + c] *
                         (double)kqv[(r0 + j) * KSTR + 64 + c];
                double lim = (j <= i) ? 1e5 : -1e5;
                sc[i * 11 + j] = fmin(s, lim);
            }
        }
        __syncthreads();
        // softmax over j (f64)
        if (lane < 10) {
            int i = lane;
            double vals[10];
            double mx = -1e300;
            #pragma unroll
            for (int j = 0; j < 10; ++j) { vals[j] = sc[i * 11 + j]; mx = fmax(mx, vals[j]); }
            double sum = 0.0;
            #pragma unroll
            for (int j = 0; j < 10; ++j) { vals[j] = exp(vals[j] - mx); sum += vals[j]; }
            double inv = 1.0 / sum;
            #pragma unroll
            for (int j = 0; j < 10; ++j) sc[i * 11 + j] = vals[j] * inv;
        }
        __syncthreads();
        // PV (f64) + f32 store: lane = output column
        size_t ob = (size_t)(blockIdx.x * 8 + bloc) * 640;
        #pragma unroll
        for (int i = 0; i < 10; ++i) {
            double o = 0.0;
            #pragma unroll
            for (int j = 0; j < 10; ++j)
                o += sc[i * 11 + j] * (double)kqv[(r0 + j) * KSTR + 128 + lane];
            out[ob + (size_t)i * 64 + lane] = (float)o;
        }
        __syncthreads();
    }
}

extern "C" void kernel_launch(void* const* d_in, const int* in_sizes, int n_in,
                              void* d_out, int out_size, void* d_ws, size_t ws_size,
                              hipStream_t stream) {
    const float* x  = (const float*)d_in[0];
    const float* wk = (const float*)d_in[1];
    const float* wq = (const float*)d_in[2];
    const float* wv = (const float*)d_in[3];
    unsigned short* wth = (unsigned short*)d_ws;          // 3 x 192*1024 bf16
    unsigned short* wtm = wth + 192 * 1024;
    unsigned short* wtl = wtm + 192 * 1024;
    float* outp = (float*)d_out;                          // FLOAT32 output

    prep_w<<<768, 256, 0, stream>>>(wk, wq, wv, wth, wtm, wtl);
    fused_attn<<<2048, 256, 0, stream>>>(x, wth, wtm, wtl, outp);
}